// Round 1
// baseline (285.221 us; speedup 1.0000x reference)
//
#include <hip/hip_runtime.h>
#include <hip/hip_bf16.h>

// MultiLoRA forward, split into two streaming kernels through d_ws:
//   K1: Bx[row,r] = sum_i x[row,i]*B[a,r,i]   (read-bound: 134 MB of x)
//   K2: out[row,o] = sum_r Bx[row,r]*A[a,o,r] (write-bound: 134 MB of out)
// SCALING = 16/16 = 1. f32 I/O, bf16 MFMA compute (same numeric path as the
// previous fused kernel: Bx rounded to bf16 once, A rounded to bf16, f32 acc).
//
// Rationale: the op is memory-streaming (2.1 GFLOP total); the fused kernel's
// 512-block grid (2 blocks/CU) serialized its read phase and write phase.
// Split kernels each get a clean, independently-sized grid; K2 runs at full
// occupancy (32 waves/CU) and uses swapped MFMA operands so each lane stores
// 4 consecutive output floats with one dwordx4.
#define RANK   16
#define IN_F   4096
#define OUT_F  4096
#define NROWS  8192

typedef __bf16 bf16x8   __attribute__((ext_vector_type(8)));
typedef float  floatx4  __attribute__((ext_vector_type(4)));

static __device__ __forceinline__ bf16x8 cvt8(floatx4 a, floatx4 b) {
    bf16x8 r;
    r[0] = (__bf16)a[0]; r[1] = (__bf16)a[1]; r[2] = (__bf16)a[2]; r[3] = (__bf16)a[3];
    r[4] = (__bf16)b[0]; r[5] = (__bf16)b[1]; r[6] = (__bf16)b[2]; r[7] = (__bf16)b[3];
    return r;
}

// ---- K1: Bx tile per block (16 rows), K=4096 split 8 ways across waves ----
// Identical to the proven phase-1 of the fused kernel; epilogue writes the
// reduced 16x16 bf16 tile to the workspace instead of LDS.
__global__ __launch_bounds__(512, 4) void
lora_bx_kernel(const float* __restrict__ x, const float* __restrict__ Bw,
               const int* __restrict__ ids, __bf16* __restrict__ bx)
{
    const int tile = blockIdx.x;            // 0..511
    const int row0 = tile * 16;
    const int adapter = ids[row0 >> 11];    // 16 | 2048: no batch crossing
    const int tid  = threadIdx.x;
    const int wave = tid >> 6;              // 0..7
    const int lane = tid & 63;

    __shared__ float red[8][256];

    const int m    = lane & 15;             // x row (and C col = r via lane)
    const int quad = lane >> 4;
    const int k0   = wave * 512 + quad * 8;
    const float* xp = x + (size_t)(row0 + m) * IN_F + k0;
    const float* bp = Bw + (size_t)adapter * (RANK * IN_F) + m * IN_F + k0;

    floatx4 acc = {0.f, 0.f, 0.f, 0.f};
#pragma unroll
    for (int s = 0; s < 16; ++s) {          // 16 steps of k32
        floatx4 xa = *reinterpret_cast<const floatx4*>(xp + s * 32);
        floatx4 xb = *reinterpret_cast<const floatx4*>(xp + s * 32 + 4);
        floatx4 ba = *reinterpret_cast<const floatx4*>(bp + s * 32);
        floatx4 bb = *reinterpret_cast<const floatx4*>(bp + s * 32 + 4);
        acc = __builtin_amdgcn_mfma_f32_16x16x32_bf16(
            cvt8(xa, xb), cvt8(ba, bb), acc, 0, 0, 0);
    }
    // C layout: row = quad*4 + j (x-row), col = lane&15 (= r)
#pragma unroll
    for (int j = 0; j < 4; ++j)
        red[wave][(quad * 4 + j) * 16 + m] = acc[j];
    __syncthreads();
    if (tid < 256) {                        // t = (row%16)*16 + r
        float s = ((red[0][tid] + red[1][tid]) + (red[2][tid] + red[3][tid]))
                + ((red[4][tid] + red[5][tid]) + (red[6][tid] + red[7][tid]));
        bx[tile * 256 + tid] = (__bf16)s;   // [row%16][r] row-major
    }
}

// ---- K2: out = Bx * A^T, swapped-operand MFMA for contiguous stores -------
// C[i][j] = sum_k Aop[i][k]*Bop[k][j] with Aop[i][k] = A[a][o0+i][k] and
// Bop[k][j] = Bx[row0+j][k]  (k = r, zero-padded 16..31).
// Lane layouts (verified by phase-1 of the previous kernel, m89 mapping):
//   A-op: row = lane&15, k = (lane>>4)*8 + i   -> lane loads A[o0+rl][q*8..+7]
//   B-op: col = lane&15, k = (lane>>4)*8 + i   -> lane loads Bx[row0+rl][q*8..+7]
//   C   : col = lane&15 (= out row), row = (lane>>4)*4+reg (= out col)
// => each lane's c[0..3] are 4 consecutive output floats: one dwordx4 store.
__global__ __launch_bounds__(256, 8) void
lora_out_kernel(const float* __restrict__ Aw, const __bf16* __restrict__ bx,
                const int* __restrict__ ids, float* __restrict__ out)
{
    const int blk      = blockIdx.x;        // 0..2047
    const int row_tile = blk >> 2;          // 512 row tiles of 16
    const int ochunk   = blk & 3;           // 4 chunks of 1024 out cols
    const int row0     = row_tile * 16;
    const int adapter  = ids[row0 >> 11];
    const int tid  = threadIdx.x;
    const int wave = tid >> 6;              // 0..3
    const int lane = tid & 63;
    const int rl   = lane & 15;
    const int quad = lane >> 4;

    bf16x8 zfrag;
#pragma unroll
    for (int i = 0; i < 8; ++i) zfrag[i] = (__bf16)0.f;

    // B-op fragment: fixed per wave (row tile fixed). Quads 2,3 carry k=16..31
    // which is zero-padded (both operands zeroed so 0*garbage can't make NaN).
    bf16x8 bfrag = zfrag;
    if (quad < 2)
        bfrag = *reinterpret_cast<const bf16x8*>(bx + row0 * 16 + rl * 16 + quad * 8);

    const float* ap = Aw + (size_t)adapter * (OUT_F * RANK);
    const int o_base = ochunk * 1024 + wave * 256;

#pragma unroll 4
    for (int t = 0; t < 16; ++t) {          // 16 o-tiles of 16 -> o span 256
        const int o0 = o_base + t * 16;
        bf16x8 afrag = zfrag;
        if (quad < 2) {
            floatx4 fa = *reinterpret_cast<const floatx4*>(
                ap + (size_t)(o0 + rl) * RANK + quad * 8);
            floatx4 fb = *reinterpret_cast<const floatx4*>(
                ap + (size_t)(o0 + rl) * RANK + quad * 8 + 4);
            afrag = cvt8(fa, fb);
        }
        floatx4 c = {0.f, 0.f, 0.f, 0.f};
        c = __builtin_amdgcn_mfma_f32_16x16x32_bf16(afrag, bfrag, c, 0, 0, 0);
        // c[reg] -> out[row0+rl][o0 + quad*4 + reg]: 16B-aligned dwordx4
        *reinterpret_cast<floatx4*>(
            out + (size_t)(row0 + rl) * OUT_F + o0 + quad * 4) = c;
    }
}

extern "C" void kernel_launch(void* const* d_in, const int* in_sizes, int n_in,
                              void* d_out, int out_size, void* d_ws, size_t ws_size,
                              hipStream_t stream) {
    const float* x   = (const float*)d_in[0]; // [4, 2048, 4096] f32
    const float* Aw  = (const float*)d_in[1]; // [8, 4096, 16]   f32
    const float* Bw  = (const float*)d_in[2]; // [8, 16, 4096]   f32
    const int*   ids = (const int*)d_in[3];   // [4] int32
    float* out = (float*)d_out;               // [4, 2048, 4096] f32

    __bf16* bxws = (__bf16*)d_ws;             // 8192*16 bf16 = 256 KB

    lora_bx_kernel<<<dim3(NROWS / 16), dim3(512), 0, stream>>>(x, Bw, ids, bxws);
    lora_out_kernel<<<dim3(2048), dim3(256), 0, stream>>>(Aw, bxws, ids, out);
}

// Round 2
// 283.859 us; speedup vs baseline: 1.0048x; 1.0048x over previous
//
#include <hip/hip_runtime.h>
#include <hip/hip_bf16.h>

// MultiLoRA forward, split into two streaming kernels:
//   K1: Bx[row,r] = sum_i x[row,i]*B[a,r,i]   (read-bound: 134 MB of x)
//   K2: out[row,o] = sum_r Bx[row,r]*A[a,o,r] (write-bound: 134 MB of out)
// SCALING = 16/16 = 1. f32 I/O, bf16 MFMA compute.
//
// Round-1 lesson: staging Bx in d_ws triggers a 537 MB poison fill (~85 us)
// per timed iteration — the fill dominated the measurement. The 256 KB Bx
// buffer now lives in a static __device__ global: allocated at module load,
// not poisoned, legal under graph capture. K1 fully rewrites it before K2
// reads (same-stream ordering), so iteration state is clean.
#define RANK   16
#define IN_F   4096
#define OUT_F  4096
#define NROWS  8192

typedef __bf16 bf16x8   __attribute__((ext_vector_type(8)));
typedef float  floatx4  __attribute__((ext_vector_type(4)));

__device__ __bf16 g_bx[NROWS * RANK];   // 256 KB staging, [row][r] row-major

static __device__ __forceinline__ bf16x8 cvt8(floatx4 a, floatx4 b) {
    bf16x8 r;
    r[0] = (__bf16)a[0]; r[1] = (__bf16)a[1]; r[2] = (__bf16)a[2]; r[3] = (__bf16)a[3];
    r[4] = (__bf16)b[0]; r[5] = (__bf16)b[1]; r[6] = (__bf16)b[2]; r[7] = (__bf16)b[3];
    return r;
}

// ---- K1: Bx tile per block (16 rows), K=4096 split 8 ways across waves ----
__global__ __launch_bounds__(512, 4) void
lora_bx_kernel(const float* __restrict__ x, const float* __restrict__ Bw,
               const int* __restrict__ ids)
{
    const int tile = blockIdx.x;            // 0..511
    const int row0 = tile * 16;
    const int adapter = ids[row0 >> 11];    // 16 | 2048: no batch crossing
    const int tid  = threadIdx.x;
    const int wave = tid >> 6;              // 0..7
    const int lane = tid & 63;

    __shared__ float red[8][256];

    const int m    = lane & 15;             // x row (and C col = r via lane)
    const int quad = lane >> 4;
    const int k0   = wave * 512 + quad * 8;
    const float* xp = x + (size_t)(row0 + m) * IN_F + k0;
    const float* bp = Bw + (size_t)adapter * (RANK * IN_F) + m * IN_F + k0;

    floatx4 acc = {0.f, 0.f, 0.f, 0.f};
#pragma unroll
    for (int s = 0; s < 16; ++s) {          // 16 steps of k32
        floatx4 xa = *reinterpret_cast<const floatx4*>(xp + s * 32);
        floatx4 xb = *reinterpret_cast<const floatx4*>(xp + s * 32 + 4);
        floatx4 ba = *reinterpret_cast<const floatx4*>(bp + s * 32);
        floatx4 bb = *reinterpret_cast<const floatx4*>(bp + s * 32 + 4);
        acc = __builtin_amdgcn_mfma_f32_16x16x32_bf16(
            cvt8(xa, xb), cvt8(ba, bb), acc, 0, 0, 0);
    }
    // C layout: row = quad*4 + j (x-row), col = lane&15 (= r)
#pragma unroll
    for (int j = 0; j < 4; ++j)
        red[wave][(quad * 4 + j) * 16 + m] = acc[j];
    __syncthreads();
    if (tid < 256) {                        // t = (row%16)*16 + r
        float s = ((red[0][tid] + red[1][tid]) + (red[2][tid] + red[3][tid]))
                + ((red[4][tid] + red[5][tid]) + (red[6][tid] + red[7][tid]));
        g_bx[tile * 256 + tid] = (__bf16)s;
    }
}

// ---- K2: out = Bx * A^T, swapped-operand MFMA for contiguous stores -------
// C[i][j] = sum_k Aop[i][k]*Bop[k][j] with Aop[i][k] = A[a][o0+i][k] and
// Bop[k][j] = Bx[row0+j][k]  (k = r, zero-padded 16..31).
// Lane layouts:
//   A-op: row = lane&15, k = (lane>>4)*8 + i   -> lane loads A[o0+rl][q*8..+7]
//   B-op: col = lane&15, k = (lane>>4)*8 + i   -> lane loads Bx[row0+rl][q*8..+7]
//   C   : col = lane&15 (= out row), row = (lane>>4)*4+reg (= out col)
// => each lane's c[0..3] are 4 consecutive output floats: one dwordx4 store.
__global__ __launch_bounds__(256, 8) void
lora_out_kernel(const float* __restrict__ Aw, const int* __restrict__ ids,
                float* __restrict__ out)
{
    const int blk      = blockIdx.x;        // 0..2047
    const int row_tile = blk >> 2;          // 512 row tiles of 16
    const int ochunk   = blk & 3;           // 4 chunks of 1024 out cols
    const int row0     = row_tile * 16;
    const int adapter  = ids[row0 >> 11];
    const int tid  = threadIdx.x;
    const int wave = tid >> 6;              // 0..3
    const int lane = tid & 63;
    const int rl   = lane & 15;
    const int quad = lane >> 4;

    bf16x8 zfrag;
#pragma unroll
    for (int i = 0; i < 8; ++i) zfrag[i] = (__bf16)0.f;

    // B-op fragment: fixed per wave (row tile fixed). Quads 2,3 carry k=16..31
    // which is zero-padded (both operands zeroed so 0*garbage can't make NaN).
    bf16x8 bfrag = zfrag;
    if (quad < 2)
        bfrag = *reinterpret_cast<const bf16x8*>(g_bx + row0 * 16 + rl * 16 + quad * 8);

    const float* ap = Aw + (size_t)adapter * (OUT_F * RANK);
    const int o_base = ochunk * 1024 + wave * 256;

#pragma unroll 4
    for (int t = 0; t < 16; ++t) {          // 16 o-tiles of 16 -> o span 256
        const int o0 = o_base + t * 16;
        bf16x8 afrag = zfrag;
        if (quad < 2) {
            floatx4 fa = *reinterpret_cast<const floatx4*>(
                ap + (size_t)(o0 + rl) * RANK + quad * 8);
            floatx4 fb = *reinterpret_cast<const floatx4*>(
                ap + (size_t)(o0 + rl) * RANK + quad * 8 + 4);
            afrag = cvt8(fa, fb);
        }
        floatx4 c = {0.f, 0.f, 0.f, 0.f};
        c = __builtin_amdgcn_mfma_f32_16x16x32_bf16(afrag, bfrag, c, 0, 0, 0);
        // c[reg] -> out[row0+rl][o0 + quad*4 + reg]: 16B-aligned dwordx4
        *reinterpret_cast<floatx4*>(
            out + (size_t)(row0 + rl) * OUT_F + o0 + quad * 4) = c;
    }
}

extern "C" void kernel_launch(void* const* d_in, const int* in_sizes, int n_in,
                              void* d_out, int out_size, void* d_ws, size_t ws_size,
                              hipStream_t stream) {
    const float* x   = (const float*)d_in[0]; // [4, 2048, 4096] f32
    const float* Aw  = (const float*)d_in[1]; // [8, 4096, 16]   f32
    const float* Bw  = (const float*)d_in[2]; // [8, 16, 4096]   f32
    const int*   ids = (const int*)d_in[3];   // [4] int32
    float* out = (float*)d_out;               // [4, 2048, 4096] f32

    lora_bx_kernel<<<dim3(NROWS / 16), dim3(512), 0, stream>>>(x, Bw, ids);
    lora_out_kernel<<<dim3(2048), dim3(256), 0, stream>>>(Aw, ids, out);
}

// Round 3
// 283.307 us; speedup vs baseline: 1.0068x; 1.0019x over previous
//
#include <hip/hip_runtime.h>
#include <hip/hip_bf16.h>

// MultiLoRA forward, split into two streaming kernels:
//   K1: partial Bx[kq][row,r] = sum_{k in quarter kq} x[row,k]*B[a,r,k]
//   K2: out[row,o] = sum_r (sum_kq Bx_part) * A[a,o,r]
// SCALING = 16/16 = 1. f32 I/O, bf16 MFMA compute, f32 cross-k accumulation
// (same numeric path as before: Bx rounded to bf16 once, A rounded to bf16).
//
// Round-2 lesson: the 537 MB d_ws poison fill (~85 us) is UNCONDITIONAL —
// present every round, not triggered by d_ws use. Subtracting it as a fixed
// cost shows the round-1/2 split kernels sum to ~123 us vs 88.5 us fused:
// both latency-bound. K1 had 2 blocks/CU (16 waves/CU) and VGPR=36 (~1
// K-step of loads in flight). This version maximizes TLP+ILP:
//   K1: K split 4-ways across blocks -> 2048 blocks x 256 thr = 8 blocks/CU
//       = 32 waves/CU, 8-step chain per wave, explicit 2-deep load pipeline,
//       f32 partials to a device-global (no atomics, no zeroing).
//   K2: proven swapped-operand MFMA; B-fragment = sum of 4 f32 partials.
#define RANK   16
#define IN_F   4096
#define OUT_F  4096
#define NROWS  8192
#define KSPLIT 4

typedef __bf16 bf16x8   __attribute__((ext_vector_type(8)));
typedef float  floatx4  __attribute__((ext_vector_type(4)));

__device__ float g_part[KSPLIT * NROWS * RANK];   // 2 MB f32 partial Bx

static __device__ __forceinline__ bf16x8 cvt8(floatx4 a, floatx4 b) {
    bf16x8 r;
    r[0] = (__bf16)a[0]; r[1] = (__bf16)a[1]; r[2] = (__bf16)a[2]; r[3] = (__bf16)a[3];
    r[4] = (__bf16)b[0]; r[5] = (__bf16)b[1]; r[6] = (__bf16)b[2]; r[7] = (__bf16)b[3];
    return r;
}

// ---- K1: 16-row tile x 1024-k quarter per block, 4 waves k-split -----------
// MFMA 16x16x32: A-op row = lane&15 (x row), k = (lane>>4)*8 + j;
// B-op col = lane&15 (= r), same k; C: row = quad*4+j (x row), col = lane&15 (r).
__global__ __launch_bounds__(256, 8) void
lora_bx_kernel(const float* __restrict__ x, const float* __restrict__ Bw,
               const int* __restrict__ ids)
{
    const int blk  = blockIdx.x;            // 0..2047
    const int rt   = blk >> 2;              // row tile 0..511
    const int kq   = blk & 3;               // k quarter
    const int row0 = rt * 16;
    const int adapter = ids[row0 >> 11];    // 16 | 2048: no batch crossing
    const int tid  = threadIdx.x;
    const int wave = tid >> 6;              // 0..3
    const int lane = tid & 63;

    __shared__ float red[4][256];

    const int m    = lane & 15;             // x row (and r via B-op col)
    const int quad = lane >> 4;
    const int k0   = kq * 1024 + wave * 256 + quad * 8;
    const float* xp = x + (size_t)(row0 + m) * IN_F + k0;
    const float* bp = Bw + (size_t)adapter * (RANK * IN_F) + m * IN_F + k0;

    // 8 steps of k32, explicit 2-deep load pipeline (fits 64-VGPR budget).
    floatx4 acc = {0.f, 0.f, 0.f, 0.f};
    floatx4 xa = *reinterpret_cast<const floatx4*>(xp);
    floatx4 xb = *reinterpret_cast<const floatx4*>(xp + 4);
    floatx4 ba = *reinterpret_cast<const floatx4*>(bp);
    floatx4 bb = *reinterpret_cast<const floatx4*>(bp + 4);
#pragma unroll
    for (int s = 0; s < 8; ++s) {
        floatx4 xa2, xb2, ba2, bb2;
        if (s < 7) {
            xa2 = *reinterpret_cast<const floatx4*>(xp + (s + 1) * 32);
            xb2 = *reinterpret_cast<const floatx4*>(xp + (s + 1) * 32 + 4);
            ba2 = *reinterpret_cast<const floatx4*>(bp + (s + 1) * 32);
            bb2 = *reinterpret_cast<const floatx4*>(bp + (s + 1) * 32 + 4);
        }
        acc = __builtin_amdgcn_mfma_f32_16x16x32_bf16(
            cvt8(xa, xb), cvt8(ba, bb), acc, 0, 0, 0);
        xa = xa2; xb = xb2; ba = ba2; bb = bb2;
    }
#pragma unroll
    for (int j = 0; j < 4; ++j)
        red[wave][(quad * 4 + j) * 16 + m] = acc[j];
    __syncthreads();
    // tid = (row%16)*16 + r; coalesced 1 KB partial-tile store.
    const float s = (red[0][tid] + red[1][tid]) + (red[2][tid] + red[3][tid]);
    g_part[((size_t)kq * NROWS + row0) * RANK + tid] = s;
}

// ---- K2: out = Bx * A^T, swapped-operand MFMA for contiguous stores -------
// C[i][j] = sum_k Aop[i][k]*Bop[k][j], Aop[i][k]=A[a][o0+i][k],
// Bop[k][j]=Bx[row0+j][k] (k = r, zero-padded 16..31).
//   A-op: row = lane&15, k = (lane>>4)*8 + i
//   B-op: col = lane&15, k = (lane>>4)*8 + i
//   C   : col = lane&15 (= out row), row = (lane>>4)*4+reg (= out col)
// => each lane's c[0..3] are 4 consecutive output floats: one dwordx4 store.
__global__ __launch_bounds__(256, 8) void
lora_out_kernel(const float* __restrict__ Aw, const int* __restrict__ ids,
                float* __restrict__ out)
{
    const int blk      = blockIdx.x;        // 0..2047
    const int row_tile = blk >> 2;          // 512 row tiles of 16
    const int ochunk   = blk & 3;           // 4 chunks of 1024 out cols
    const int row0     = row_tile * 16;
    const int adapter  = ids[row0 >> 11];
    const int tid  = threadIdx.x;
    const int wave = tid >> 6;              // 0..3
    const int lane = tid & 63;
    const int rl   = lane & 15;
    const int quad = lane >> 4;

    bf16x8 zfrag;
#pragma unroll
    for (int i = 0; i < 8; ++i) zfrag[i] = (__bf16)0.f;

    // B-op fragment: sum the 4 f32 k-quarter partials (L2-resident, 2 MB),
    // then round to bf16 once. Quads 2,3 carry k=16..31 -> zero-padded.
    bf16x8 bfrag = zfrag;
    if (quad < 2) {
        const float* pp = g_part + ((size_t)(row0 + rl)) * RANK + quad * 8;
        floatx4 s0 = {0.f, 0.f, 0.f, 0.f}, s1 = {0.f, 0.f, 0.f, 0.f};
#pragma unroll
        for (int p = 0; p < KSPLIT; ++p) {
            s0 += *reinterpret_cast<const floatx4*>(pp + (size_t)p * NROWS * RANK);
            s1 += *reinterpret_cast<const floatx4*>(pp + (size_t)p * NROWS * RANK + 4);
        }
        bfrag = cvt8(s0, s1);
    }

    const float* ap = Aw + (size_t)adapter * (OUT_F * RANK);
    const int o_base = ochunk * 1024 + wave * 256;

#pragma unroll 4
    for (int t = 0; t < 16; ++t) {          // 16 o-tiles of 16 -> o span 256
        const int o0 = o_base + t * 16;
        bf16x8 afrag = zfrag;
        if (quad < 2) {
            floatx4 fa = *reinterpret_cast<const floatx4*>(
                ap + (size_t)(o0 + rl) * RANK + quad * 8);
            floatx4 fb = *reinterpret_cast<const floatx4*>(
                ap + (size_t)(o0 + rl) * RANK + quad * 8 + 4);
            afrag = cvt8(fa, fb);
        }
        floatx4 c = {0.f, 0.f, 0.f, 0.f};
        c = __builtin_amdgcn_mfma_f32_16x16x32_bf16(afrag, bfrag, c, 0, 0, 0);
        // c[reg] -> out[row0+rl][o0 + quad*4 + reg]: 16B-aligned dwordx4
        *reinterpret_cast<floatx4*>(
            out + (size_t)(row0 + rl) * OUT_F + o0 + quad * 4) = c;
    }
}

extern "C" void kernel_launch(void* const* d_in, const int* in_sizes, int n_in,
                              void* d_out, int out_size, void* d_ws, size_t ws_size,
                              hipStream_t stream) {
    const float* x   = (const float*)d_in[0]; // [4, 2048, 4096] f32
    const float* Aw  = (const float*)d_in[1]; // [8, 4096, 16]   f32
    const float* Bw  = (const float*)d_in[2]; // [8, 16, 4096]   f32
    const int*   ids = (const int*)d_in[3];   // [4] int32
    float* out = (float*)d_out;               // [4, 2048, 4096] f32

    lora_bx_kernel<<<dim3(NROWS / 16 * KSPLIT), dim3(256), 0, stream>>>(x, Bw, ids);
    lora_out_kernel<<<dim3(2048), dim3(256), 0, stream>>>(Aw, ids, out);
}

// Round 4
// 263.189 us; speedup vs baseline: 1.0837x; 1.0764x over previous
//
#include <hip/hip_runtime.h>
#include <hip/hip_bf16.h>

// MultiLoRA forward, single fused kernel (split overhead was ~35 us pure loss).
//   out[row,o] = sum_r (sum_i x[row,i]*B[a,r,i]) * A[a,o,r],  a = ids[row/2048]
// SCALING = 16/16 = 1. f32 I/O, bf16 MFMA compute (numerics identical to the
// round-0 kernel: Bx rounded to bf16 once, A rounded to bf16, f32 accum).
//
// Round-3 lesson: raising occupancy/pipelining did NOT move the split kernels
// (~122 us in rounds 1-3) -> the limiter is per-instruction access
// granularity, not TLP. MFMA-fragment-shaped global loads touch 16 rows
// (16 KB stride) at 16-32 B per row per instruction (~32 half-used cache
// lines / KB); the 6.3 TB/s fill kernel moves 1 KB fully-linear per instr.
// Fix: decouple global pattern from compute pattern:
//   - Phase 1 stages x and B chunks [16 rows][256 k] f32 into LDS with
//     global_load_lds width=16 -> each instruction = 1 KB contiguous from ONE
//     row. Double-buffered, counted s_waitcnt vmcnt(4) (never 0 mid-loop).
//     MFMA fragments then come from LDS (ds_read_b128, pad 260 floats/row:
//     bank-balanced at the b128 8-access floor).
//   - Phase 2 = round-2-verified swapped-operand MFMA epilogue (each lane
//     stores 4 consecutive floats, full 64-B lines per row), NT stores.
//   - XCD-bijective swizzle (512 tiles = 8 XCDs x 64) for per-XCD contiguity.
#define RANK   16
#define IN_F   4096
#define OUT_F  4096
#define NROWS  8192
#define NTILES (NROWS / 16)     // 512
#define CK     256              // k-chunk in floats (1 KB per row)
#define NC     (IN_F / CK)      // 16 chunks
#define LDSP   260              // padded LDS row stride (floats); 1040 B, 16B-aligned

typedef __bf16 bf16x8  __attribute__((ext_vector_type(8)));
typedef float  floatx4 __attribute__((ext_vector_type(4)));

static __device__ __forceinline__ bf16x8 cvt8(floatx4 a, floatx4 b) {
    bf16x8 r;
    r[0] = (__bf16)a[0]; r[1] = (__bf16)a[1]; r[2] = (__bf16)a[2]; r[3] = (__bf16)a[3];
    r[4] = (__bf16)b[0]; r[5] = (__bf16)b[1]; r[6] = (__bf16)b[2]; r[7] = (__bf16)b[3];
    return r;
}

// One wave-instruction: 64 lanes x 16 B = 1 KB linear global -> 1 KB linear LDS.
// LDS dest must be wave-uniform (HW writes base + lane*16); global src is per-lane.
static __device__ __forceinline__ void stage16(const float* g, float* l) {
    __builtin_amdgcn_global_load_lds(
        (const __attribute__((address_space(1))) void*)g,
        (__attribute__((address_space(3))) void*)l, 16, 0, 0);
}

__global__ __launch_bounds__(512, 4) void
lora_fused2_kernel(const float* __restrict__ x, const float* __restrict__ Aw,
                   const float* __restrict__ Bw, const int* __restrict__ ids,
                   float* __restrict__ out)
{
    // Bijective XCD swizzle: 512 tiles = 8 XCDs x 64 contiguous tiles each.
    const int b    = blockIdx.x;
    const int tile = (b & 7) * (NTILES / 8) + (b >> 3);
    const int row0 = tile * 16;
    const int adapter = ids[row0 >> 11];    // 16 | 2048: no batch crossing
    const int tid  = threadIdx.x;
    const int wave = tid >> 6;              // 0..7
    const int lane = tid & 63;
    const int m    = lane & 15;             // frag row (x row / B r / out row)
    const int quad = lane >> 4;

    __shared__ float  xs [2][16][LDSP];     // staged x chunk, f32
    __shared__ float  bsh[2][16][LDSP];     // staged B chunk, f32
    __shared__ float  red[8][256];          // cross-wave Bx reduce
    __shared__ __bf16 bxs[256];             // Bx tile [row%16][r] bf16

    // Per-wave stage sources: wave w owns x rows {2w,2w+1} and B rows {2w,2w+1}.
    const float* xrow = x  + (size_t)(row0 + 2 * wave) * IN_F + lane * 4;
    const float* brow = Bw + ((size_t)adapter * RANK + 2 * wave) * IN_F + lane * 4;

    // ---- Phase 1: Bx[row,r] = sum_k x[row,k]*B[a,r,k], LDS-staged chunks ----
    auto STAGE = [&](int c, int bf) {       // 4 instrs/wave/chunk -> vmcnt(4)
        const float* xsrc = xrow + c * CK;
        const float* bsrc = brow + c * CK;
        stage16(xsrc,        &xs [bf][2 * wave    ][0]);
        stage16(xsrc + IN_F, &xs [bf][2 * wave + 1][0]);
        stage16(bsrc,        &bsh[bf][2 * wave    ][0]);
        stage16(bsrc + IN_F, &bsh[bf][2 * wave + 1][0]);
    };

    floatx4 acc = {0.f, 0.f, 0.f, 0.f};
    const int koff = wave * 32 + quad * 8;  // wave w computes k-local w*32..+31

    auto COMPUTE = [&](int bf) {
        floatx4 xa = *reinterpret_cast<const floatx4*>(&xs [bf][m][koff]);
        floatx4 xb = *reinterpret_cast<const floatx4*>(&xs [bf][m][koff + 4]);
        floatx4 ba = *reinterpret_cast<const floatx4*>(&bsh[bf][m][koff]);
        floatx4 bb = *reinterpret_cast<const floatx4*>(&bsh[bf][m][koff + 4]);
        acc = __builtin_amdgcn_mfma_f32_16x16x32_bf16(
            cvt8(xa, xb), cvt8(ba, bb), acc, 0, 0, 0);
    };

    STAGE(0, 0);
    int bf = 0;
    for (int c = 0; c < NC - 1; ++c) {
        STAGE(c + 1, bf ^ 1);               // prefetch next chunk
        // Drain only the OLDEST 4 loads (chunk c); chunk c+1 stays in flight.
        asm volatile("s_waitcnt vmcnt(4)" ::: "memory");
        __builtin_amdgcn_sched_barrier(0);
        __syncthreads();                    // all waves' chunk-c data in LDS
        COMPUTE(bf);
        __syncthreads();                    // protect buf before re-stage
        bf ^= 1;
    }
    asm volatile("s_waitcnt vmcnt(0)" ::: "memory");
    __builtin_amdgcn_sched_barrier(0);
    __syncthreads();
    COMPUTE(bf);

    // C layout: row = quad*4 + j (x-row), col = m (= r). Reduce 8 waves.
#pragma unroll
    for (int j = 0; j < 4; ++j)
        red[wave][(quad * 4 + j) * 16 + m] = acc[j];
    __syncthreads();
    if (tid < 256) {                        // t = (row%16)*16 + r
        float s = ((red[0][tid] + red[1][tid]) + (red[2][tid] + red[3][tid]))
                + ((red[4][tid] + red[5][tid]) + (red[6][tid] + red[7][tid]));
        bxs[tid] = (__bf16)s;
    }
    __syncthreads();

    // ---- Phase 2: out = Bx * A^T, swapped-operand MFMA (round-2 verified) --
    // A-op: row = m (= A row o0+m), k = quad*8+i; B-op: col = m (= out row),
    // k = quad*8+i (k=r, zero-padded 16..31).
    // C: col = m (= out row), row = quad*4+reg (= out col) -> dwordx4 store.
    bf16x8 zfrag;
#pragma unroll
    for (int i = 0; i < 8; ++i) zfrag[i] = (__bf16)0.f;

    bf16x8 bfrag = zfrag;
    if (quad < 2)
        bfrag = *reinterpret_cast<const bf16x8*>(bxs + m * 16 + quad * 8);

    const float* ap = Aw + (size_t)adapter * (OUT_F * RANK);
    const int o_base = wave * 512;          // 8 waves x 512 cols = 4096

#pragma unroll 4
    for (int t = 0; t < 32; ++t) {
        const int o0 = o_base + t * 16;
        bf16x8 afrag = zfrag;
        if (quad < 2) {
            floatx4 fa = *reinterpret_cast<const floatx4*>(
                ap + (size_t)(o0 + m) * RANK + quad * 8);
            floatx4 fb = *reinterpret_cast<const floatx4*>(
                ap + (size_t)(o0 + m) * RANK + quad * 8 + 4);
            afrag = cvt8(fa, fb);
        }
        floatx4 c4 = {0.f, 0.f, 0.f, 0.f};
        c4 = __builtin_amdgcn_mfma_f32_16x16x32_bf16(afrag, bfrag, c4, 0, 0, 0);
        __builtin_nontemporal_store(
            c4, reinterpret_cast<floatx4*>(
                    out + (size_t)(row0 + m) * OUT_F + o0 + quad * 4));
    }
}

extern "C" void kernel_launch(void* const* d_in, const int* in_sizes, int n_in,
                              void* d_out, int out_size, void* d_ws, size_t ws_size,
                              hipStream_t stream) {
    const float* x   = (const float*)d_in[0]; // [4, 2048, 4096] f32
    const float* Aw  = (const float*)d_in[1]; // [8, 4096, 16]   f32
    const float* Bw  = (const float*)d_in[2]; // [8, 16, 4096]   f32
    const int*   ids = (const int*)d_in[3];   // [4] int32
    float* out = (float*)d_out;               // [4, 2048, 4096] f32

    lora_fused2_kernel<<<dim3(NTILES), dim3(512), 0, stream>>>(x, Aw, Bw, ids, out);
}

// Round 5
// 253.130 us; speedup vs baseline: 1.1268x; 1.0397x over previous
//
#include <hip/hip_runtime.h>
#include <hip/hip_bf16.h>

// MultiLoRA forward, two streaming kernels + f32 staging through a device global:
//   K1: Bx[row,r] = sum_i x[row,i]*B[a,r,i]   (MFMA, read 134 MB of x)
//   K2: out[row,o] = sum_r Bx[row,r]*A[a,o,r] (pure-VALU f32, write 134 MB)
// SCALING = 16/16 = 1.
//
// R0-R4 ledger (kernel-only = dur_us - ~160 fixed harness cost):
//   R0 fused 88.5 | R1/R2/R3 split ~123 (INVARIANT across K1 redesigns)
//   R4 LDS-staged fused 105 (linear loads did NOT help; NT stores +14% WRITE)
// Inference: K2 (write phase) ~85 us is the dominant cost; its stores touch
// 16 rows x 64 B (half-lines, 16 KB apart) per instruction. The 6.3 TB/s fill
// writes 1 KB contiguous per instruction. Phase 2 is only ~537M MACs (~7 us
// of f32 VALU chip-wide) -> MFMA is unnecessary; rebuild K2 fill-shaped:
//   - lane owns 4 CONTIGUOUS out cols; A[c..c+3][0..15] lives in 64 VGPRs
//     (one 256 B contiguous load sequence per lane, per block);
//   - per row: 4 broadcast f32 loads of Bx[row][:], 64 v_fma, ONE dwordx4
//     store -> each wave store instruction = 1 KB contiguous, like the fill.
//   - phase 2 all-f32 (A no longer rounded to bf16): absmax can only improve.
// K1 = R2-proven MFMA kernel, now emitting f32 Bx.
#define RANK   16
#define IN_F   4096
#define OUT_F  4096
#define NROWS  8192

typedef __bf16 bf16x8  __attribute__((ext_vector_type(8)));
typedef float  floatx4 __attribute__((ext_vector_type(4)));

__device__ float g_bx[NROWS * RANK];   // 512 KB f32 staging, [row][r]

static __device__ __forceinline__ bf16x8 cvt8(floatx4 a, floatx4 b) {
    bf16x8 r;
    r[0] = (__bf16)a[0]; r[1] = (__bf16)a[1]; r[2] = (__bf16)a[2]; r[3] = (__bf16)a[3];
    r[4] = (__bf16)b[0]; r[5] = (__bf16)b[1]; r[6] = (__bf16)b[2]; r[7] = (__bf16)b[3];
    return r;
}

// ---- K1: Bx tile per block (16 rows), K=4096 split 8 ways across waves ----
// Proven in R1/R2 (passed, absmax 0.0039). Only change: f32 output.
__global__ __launch_bounds__(512, 4) void
lora_bx_kernel(const float* __restrict__ x, const float* __restrict__ Bw,
               const int* __restrict__ ids)
{
    const int tile = blockIdx.x;            // 0..511
    const int row0 = tile * 16;
    const int adapter = ids[row0 >> 11];    // 16 | 2048: no batch crossing
    const int tid  = threadIdx.x;
    const int wave = tid >> 6;              // 0..7
    const int lane = tid & 63;

    __shared__ float red[8][256];

    const int m    = lane & 15;             // x row (and C col = r via lane)
    const int quad = lane >> 4;
    const int k0   = wave * 512 + quad * 8;
    const float* xp = x + (size_t)(row0 + m) * IN_F + k0;
    const float* bp = Bw + (size_t)adapter * (RANK * IN_F) + m * IN_F + k0;

    floatx4 acc = {0.f, 0.f, 0.f, 0.f};
#pragma unroll
    for (int s = 0; s < 16; ++s) {          // 16 steps of k32
        floatx4 xa = *reinterpret_cast<const floatx4*>(xp + s * 32);
        floatx4 xb = *reinterpret_cast<const floatx4*>(xp + s * 32 + 4);
        floatx4 ba = *reinterpret_cast<const floatx4*>(bp + s * 32);
        floatx4 bb = *reinterpret_cast<const floatx4*>(bp + s * 32 + 4);
        acc = __builtin_amdgcn_mfma_f32_16x16x32_bf16(
            cvt8(xa, xb), cvt8(ba, bb), acc, 0, 0, 0);
    }
    // C layout: row = quad*4 + j (x-row), col = lane&15 (= r)
#pragma unroll
    for (int j = 0; j < 4; ++j)
        red[wave][(quad * 4 + j) * 16 + m] = acc[j];
    __syncthreads();
    if (tid < 256) {                        // t = (row%16)*16 + r
        float s = ((red[0][tid] + red[1][tid]) + (red[2][tid] + red[3][tid]))
                + ((red[4][tid] + red[5][tid]) + (red[6][tid] + red[7][tid]));
        g_bx[tile * 256 + tid] = s;         // f32 (no bf16 rounding of Bx)
    }
}

// ---- K2: fill-shaped writer. out[row, c] = dot16(Bx[row,:], A[a,c,:]) ----
// Block: 256 thr (4 waves). Wave w owns 256 contiguous cols; lane owns 4.
// A[c0..c0+3][0..15] preloaded to 64 VGPRs (256 B contiguous per lane).
// Row loop: 4 broadcast dwordx4 (Bx row, f32) + 64 v_fma + ONE dwordx4 store
// -> every wave store instruction covers 1 KB contiguous (fill pattern).
__global__ __launch_bounds__(256, 4) void
lora_out_kernel(const float* __restrict__ Aw, const int* __restrict__ ids,
                float* __restrict__ out)
{
    const int b    = blockIdx.x;            // 0..1023
    const int cc   = b & 3;                 // col chunk of 1024
    const int rg   = b >> 2;                // row group of 32 (0..255)
    const int row0 = rg * 32;
    const int adapter = ids[row0 >> 11];    // 32 | 2048: no batch crossing
    const int tid  = threadIdx.x;
    const int wave = tid >> 6;              // 0..3
    const int lane = tid & 63;
    const int c0   = cc * 1024 + wave * 256 + lane * 4;  // 4 contiguous cols

    // Preload A[a][c0+j][r] for j=0..3, r=0..15 -> 16 dwordx4 (256 B/lane).
    const float* ap = Aw + ((size_t)adapter * OUT_F + c0) * RANK;
    floatx4 a[16];                          // a[j*4+q] = A[c0+j][q*4..q*4+3]
#pragma unroll
    for (int i = 0; i < 16; ++i)
        a[i] = *reinterpret_cast<const floatx4*>(ap + i * 4);

#pragma unroll 2
    for (int rr = 0; rr < 32; ++rr) {
        const int row = row0 + rr;
        const float* bp = g_bx + (size_t)row * RANK;    // uniform: broadcast
        const floatx4 b0 = *reinterpret_cast<const floatx4*>(bp);
        const floatx4 b1 = *reinterpret_cast<const floatx4*>(bp + 4);
        const floatx4 b2 = *reinterpret_cast<const floatx4*>(bp + 8);
        const floatx4 b3 = *reinterpret_cast<const floatx4*>(bp + 12);
        floatx4 ov;
#pragma unroll
        for (int j = 0; j < 4; ++j) {
            const floatx4 a0 = a[j * 4 + 0], a1 = a[j * 4 + 1];
            const floatx4 a2 = a[j * 4 + 2], a3 = a[j * 4 + 3];
            float s = a0[0] * b0[0] + a0[1] * b0[1] + a0[2] * b0[2] + a0[3] * b0[3]
                    + a1[0] * b1[0] + a1[1] * b1[1] + a1[2] * b1[2] + a1[3] * b1[3]
                    + a2[0] * b2[0] + a2[1] * b2[1] + a2[2] * b2[2] + a2[3] * b2[3]
                    + a3[0] * b3[0] + a3[1] * b3[1] + a3[2] * b3[2] + a3[3] * b3[3];
            ov[j] = s;
        }
        *reinterpret_cast<floatx4*>(out + (size_t)row * OUT_F + c0) = ov;
    }
}

extern "C" void kernel_launch(void* const* d_in, const int* in_sizes, int n_in,
                              void* d_out, int out_size, void* d_ws, size_t ws_size,
                              hipStream_t stream) {
    const float* x   = (const float*)d_in[0]; // [4, 2048, 4096] f32
    const float* Aw  = (const float*)d_in[1]; // [8, 4096, 16]   f32
    const float* Bw  = (const float*)d_in[2]; // [8, 16, 4096]   f32
    const int*   ids = (const int*)d_in[3];   // [4] int32
    float* out = (float*)d_out;               // [4, 2048, 4096] f32

    lora_bx_kernel <<<dim3(NROWS / 16), dim3(512), 0, stream>>>(x, Bw, ids);
    lora_out_kernel<<<dim3(1024),       dim3(256), 0, stream>>>(Aw, ids, out);
}

// Round 6
// 251.857 us; speedup vs baseline: 1.1325x; 1.0051x over previous
//
#include <hip/hip_runtime.h>
#include <hip/hip_bf16.h>

// MultiLoRA forward, two streaming kernels + f32 staging through a device global:
//   K1: Bx[row,r] = sum_i x[row,i]*B[a,r,i]   (MFMA, read 134 MB of x)
//   K2: out[row,o] = sum_r Bx[row,r]*A[a,o,r] (pure-VALU f32, write 134 MB)
// SCALING = 16/16 = 1.
//
// Ledger (kernel-only = dur_us - ~161 fixed harness cost):
//   R0 fused 88.5 | R1-R3 split ~123 | R4 LDS-staged fused 105 | R5 split 92
// R5 proved the fill-shaped VALU writer (1 KB contiguous, full 128-B lines
// per instruction) beats the MFMA-fragment writer by ~31 us.
// R6 theory: x (134 MB) + out (134 MB) > 256 MB L3 -> the zero-reuse out
// stream evicts x from Infinity Cache (R0 FETCH=74 MB proves x is only
// ~45% L3-resident). Single change vs R5: K2 stores are NONTEMPORAL.
// Full-line-covered NT stores stream to HBM without allocating in L2/L3,
// freeing L3 for x. (R4's NT regression was half-line scattered stores —
// partial NT lines RMW; does not apply to this full-line pattern.)
// Check: WRITE_SIZE must stay exactly 131072 KB.
#define RANK   16
#define IN_F   4096
#define OUT_F  4096
#define NROWS  8192

typedef __bf16 bf16x8  __attribute__((ext_vector_type(8)));
typedef float  floatx4 __attribute__((ext_vector_type(4)));

__device__ float g_bx[NROWS * RANK];   // 512 KB f32 staging, [row][r]

static __device__ __forceinline__ bf16x8 cvt8(floatx4 a, floatx4 b) {
    bf16x8 r;
    r[0] = (__bf16)a[0]; r[1] = (__bf16)a[1]; r[2] = (__bf16)a[2]; r[3] = (__bf16)a[3];
    r[4] = (__bf16)b[0]; r[5] = (__bf16)b[1]; r[6] = (__bf16)b[2]; r[7] = (__bf16)b[3];
    return r;
}

// ---- K1: Bx tile per block (16 rows), K=4096 split 8 ways across waves ----
// Proven in R1/R2/R5 (passed, absmax 0.0039). Unchanged from R5.
__global__ __launch_bounds__(512, 4) void
lora_bx_kernel(const float* __restrict__ x, const float* __restrict__ Bw,
               const int* __restrict__ ids)
{
    const int tile = blockIdx.x;            // 0..511
    const int row0 = tile * 16;
    const int adapter = ids[row0 >> 11];    // 16 | 2048: no batch crossing
    const int tid  = threadIdx.x;
    const int wave = tid >> 6;              // 0..7
    const int lane = tid & 63;

    __shared__ float red[8][256];

    const int m    = lane & 15;             // x row (and C col = r via lane)
    const int quad = lane >> 4;
    const int k0   = wave * 512 + quad * 8;
    const float* xp = x + (size_t)(row0 + m) * IN_F + k0;
    const float* bp = Bw + (size_t)adapter * (RANK * IN_F) + m * IN_F + k0;

    floatx4 acc = {0.f, 0.f, 0.f, 0.f};
#pragma unroll
    for (int s = 0; s < 16; ++s) {          // 16 steps of k32
        floatx4 xa = *reinterpret_cast<const floatx4*>(xp + s * 32);
        floatx4 xb = *reinterpret_cast<const floatx4*>(xp + s * 32 + 4);
        floatx4 ba = *reinterpret_cast<const floatx4*>(bp + s * 32);
        floatx4 bb = *reinterpret_cast<const floatx4*>(bp + s * 32 + 4);
        acc = __builtin_amdgcn_mfma_f32_16x16x32_bf16(
            cvt8(xa, xb), cvt8(ba, bb), acc, 0, 0, 0);
    }
    // C layout: row = quad*4 + j (x-row), col = lane&15 (= r)
#pragma unroll
    for (int j = 0; j < 4; ++j)
        red[wave][(quad * 4 + j) * 16 + m] = acc[j];
    __syncthreads();
    if (tid < 256) {                        // t = (row%16)*16 + r
        float s = ((red[0][tid] + red[1][tid]) + (red[2][tid] + red[3][tid]))
                + ((red[4][tid] + red[5][tid]) + (red[6][tid] + red[7][tid]));
        g_bx[tile * 256 + tid] = s;         // f32 (no bf16 rounding of Bx)
    }
}

// ---- K2: fill-shaped writer. out[row, c] = dot16(Bx[row,:], A[a,c,:]) ----
// Block: 256 thr (4 waves). Wave w owns 256 contiguous cols; lane owns 4.
// A[c0..c0+3][0..15] preloaded to 64 VGPRs (256 B contiguous per lane).
// Row loop: 4 broadcast dwordx4 (Bx row, f32) + 64 v_fma + ONE dwordx4 store
// -> every wave store instruction covers 1 KB contiguous / full 128-B lines.
// R6: the store is NONTEMPORAL (bypass L2/L3 allocation; keep L3 for x).
__global__ __launch_bounds__(256, 4) void
lora_out_kernel(const float* __restrict__ Aw, const int* __restrict__ ids,
                float* __restrict__ out)
{
    const int b    = blockIdx.x;            // 0..1023
    const int cc   = b & 3;                 // col chunk of 1024
    const int rg   = b >> 2;                // row group of 32 (0..255)
    const int row0 = rg * 32;
    const int adapter = ids[row0 >> 11];    // 32 | 2048: no batch crossing
    const int tid  = threadIdx.x;
    const int wave = tid >> 6;              // 0..3
    const int lane = tid & 63;
    const int c0   = cc * 1024 + wave * 256 + lane * 4;  // 4 contiguous cols

    // Preload A[a][c0+j][r] for j=0..3, r=0..15 -> 16 dwordx4 (256 B/lane).
    const float* ap = Aw + ((size_t)adapter * OUT_F + c0) * RANK;
    floatx4 a[16];                          // a[j*4+q] = A[c0+j][q*4..q*4+3]
#pragma unroll
    for (int i = 0; i < 16; ++i)
        a[i] = *reinterpret_cast<const floatx4*>(ap + i * 4);

#pragma unroll 2
    for (int rr = 0; rr < 32; ++rr) {
        const int row = row0 + rr;
        const float* bp = g_bx + (size_t)row * RANK;    // uniform: broadcast
        const floatx4 b0 = *reinterpret_cast<const floatx4*>(bp);
        const floatx4 b1 = *reinterpret_cast<const floatx4*>(bp + 4);
        const floatx4 b2 = *reinterpret_cast<const floatx4*>(bp + 8);
        const floatx4 b3 = *reinterpret_cast<const floatx4*>(bp + 12);
        floatx4 ov;
#pragma unroll
        for (int j = 0; j < 4; ++j) {
            const floatx4 a0 = a[j * 4 + 0], a1 = a[j * 4 + 1];
            const floatx4 a2 = a[j * 4 + 2], a3 = a[j * 4 + 3];
            float s = a0[0] * b0[0] + a0[1] * b0[1] + a0[2] * b0[2] + a0[3] * b0[3]
                    + a1[0] * b1[0] + a1[1] * b1[1] + a1[2] * b1[2] + a1[3] * b1[3]
                    + a2[0] * b2[0] + a2[1] * b2[1] + a2[2] * b2[2] + a2[3] * b2[3]
                    + a3[0] * b3[0] + a3[1] * b3[1] + a3[2] * b3[2] + a3[3] * b3[3];
            ov[j] = s;
        }
        __builtin_nontemporal_store(
            ov, reinterpret_cast<floatx4*>(out + (size_t)row * OUT_F + c0));
    }
}

extern "C" void kernel_launch(void* const* d_in, const int* in_sizes, int n_in,
                              void* d_out, int out_size, void* d_ws, size_t ws_size,
                              hipStream_t stream) {
    const float* x   = (const float*)d_in[0]; // [4, 2048, 4096] f32
    const float* Aw  = (const float*)d_in[1]; // [8, 4096, 16]   f32
    const float* Bw  = (const float*)d_in[2]; // [8, 16, 4096]   f32
    const int*   ids = (const int*)d_in[3];   // [4] int32
    float* out = (float*)d_out;               // [4, 2048, 4096] f32

    lora_bx_kernel <<<dim3(NROWS / 16), dim3(512), 0, stream>>>(x, Bw, ids);
    lora_out_kernel<<<dim3(1024),       dim3(256), 0, stream>>>(Aw, ids, out);
}